// Round 1
// baseline (118.881 us; speedup 1.0000x reference)
//
#include <hip/hip_runtime.h>
#include <hip/hip_cooperative_groups.h>
#include <math.h>

namespace cg = cooperative_groups;

// ---------------------------------------------------------------------------
// Single-launch fused Refiner (cooperative grid sync).
//
// R6: the two kernels (B pre-reduction + refine) were each ~<10us of real
// work; per-iteration cost was dominated by having two dependent dispatches.
// Fused into ONE cooperative kernel:
//   Phase A: block b computes B-entries e = 7b..7b+6 (7 x 128 threads,
//            coalesced fv reads, shfl-tree reduce) and gWTf row xx = b
//            (112 blocks x 224 = 25088 exact).
//   grid.sync()
//   Phase B: identical to the previous refine_kernel body.
//
// Carried from earlier rounds:
//  - B[s][t][u][v] = sum_c conv_w[1+c][t] * f14[s][c][u][v]; feature term of
//    every stage is one bilinear sample of B (BN affine commutes with lerp).
//  - Final up2-x folded into weights WTfold[xx][o]; kernel computes per-y4-row
//    dots D[i][o] (K=112) and lerps D rows (up2-y) at the end.
//  - Cone-pruned LDS staging of B rows; stage 1 uses integer B lookup.
// ---------------------------------------------------------------------------

#define BN_EPS 1e-5f

__device__ __forceinline__ float clampf(float x, float lo, float hi) {
    return fminf(fmaxf(x, lo), hi);
}

__device__ __forceinline__ float sampleB(const float* __restrict__ Bt, float fy, float fx) {
    int y0 = (int)fy; float by = fy - (float)y0; int y1 = min(y0 + 1, 13);
    int x0 = (int)fx; float bx = fx - (float)x0; int x1 = min(x0 + 1, 13);
    return (1.f - by) * ((1.f - bx) * Bt[y0 * 14 + x0] + bx * Bt[y0 * 14 + x1])
         + by         * ((1.f - bx) * Bt[y1 * 14 + x0] + bx * Bt[y1 * 14 + x1]);
}

// Conv accumulator (pre-ReLU/BN) for one pixel at resolution H (up-sampled h).
__device__ __forceinline__ float stage_pixel(int i, int j, int H,
                                             const float* __restrict__ hsrc, int srcH,
                                             const float* __restrict__ sB,
                                             const float* __restrict__ cw, float bias) {
    float featScale = 14.0f / (float)H;
    float srcMax = (float)(srcH - 1);
    float acc = bias;

#pragma unroll
    for (int a = 0; a < 3; ++a) {
        int p = i + a - 1;
        if (p < 0 || p >= H) continue;          // SAME zero padding
        float fy = clampf(((float)p + 0.5f) * featScale - 0.5f, 0.f, 13.f);
        float hy = clampf(((float)p + 0.5f) * 0.5f - 0.5f, 0.f, srcMax);
        int hy0 = (int)hy; float fhy = hy - (float)hy0; int hy1 = min(hy0 + 1, srcH - 1);
#pragma unroll
        for (int bq = 0; bq < 3; ++bq) {
            int q = j + bq - 1;
            if (q < 0 || q >= H) continue;
            int t = a * 3 + bq;

            float fx = clampf(((float)q + 0.5f) * featScale - 0.5f, 0.f, 13.f);
            float bv = sampleB(sB + t * 196, fy, fx);

            float hx = clampf(((float)q + 0.5f) * 0.5f - 0.5f, 0.f, srcMax);
            int hx0 = (int)hx; float fhx = hx - (float)hx0; int hx1 = min(hx0 + 1, srcH - 1);
            float hval = (1.f - fhy) * ((1.f - fhx) * hsrc[hy0 * srcH + hx0] + fhx * hsrc[hy0 * srcH + hx1])
                       + fhy         * ((1.f - fhx) * hsrc[hy1 * srcH + hx0] + fhx * hsrc[hy1 * srcH + hx1]);
            acc += cw[t] * hval + bv;
        }
    }
    return acc;
}

// src rows needed to compute dst rows [dlo,dhi] of a stage at H=2*srcH.
__device__ __forceinline__ void srcRange(int dlo, int dhi, int srcH, int& slo, int& shi) {
    int H = 2 * srcH;
    int p0 = max(dlo - 1, 0), p1 = min(dhi + 1, H - 1);
    float h0 = fmaxf(((float)p0 + 0.5f) * 0.5f - 0.5f, 0.f);
    float h1 = fmaxf(((float)p1 + 0.5f) * 0.5f - 0.5f, 0.f);
    slo = (int)h0;
    shi = min((int)h1 + 1, srcH - 1);
}

// B-plane rows of a stage's sB needed for dst rows [dlo,dhi] at resolution H.
__device__ __forceinline__ void bRange(int dlo, int dhi, int H, int& lo, int& hi) {
    float sc = 14.f / (float)H;
    int p0 = max(dlo - 1, 0), p1 = min(dhi + 1, H - 1);
    float f0 = clampf(((float)p0 + 0.5f) * sc - 0.5f, 0.f, 13.f);
    float f1 = clampf(((float)p1 + 0.5f) * sc - 0.5f, 0.f, 13.f);
    lo = (int)f0;
    hi = min((int)f1 + 1, 13);
}

__global__ __launch_bounds__(1024, 1)
void refine_fused(const float* __restrict__ x, const float* __restrict__ fv,
                  const float* __restrict__ conv_w, const float* __restrict__ conv_b,
                  const float* __restrict__ bng, const float* __restrict__ bnb,
                  const float* __restrict__ bnm, const float* __restrict__ bnv,
                  const float* __restrict__ W_w, const float* __restrict__ W_b,
                  float* __restrict__ gB, float* __restrict__ gWTf,
                  float* __restrict__ out) {
    __shared__ float sB[4 * 9 * 196];
    __shared__ float y1s[196];
    __shared__ float y2s[784];
    __shared__ float y3s[3136];
    __shared__ float y4loc[3 * 112];
    __shared__ float partial[12 * 224];   // (slot i, K-quarter kq) x o
    __shared__ float red[14][9];          // phase A cross-wave reduce

    int tid = threadIdx.x;
    int b = blockIdx.x;

    // ======================= Phase A: B entries + gWTf row =================
    // 7 B-entries per block, 128 threads (2 waves) each. 112*7 == 784 exact.
    if (tid < 896) {
        int e7 = tid >> 7, r = tid & 127;
        int e = b * 7 + e7;
        int s = e / 196, uv = e % 196;
        const float* fvrow = fv + ((size_t)(3 - s) * 197 + 1 + uv) * 768;
        float part[9];
#pragma unroll
        for (int t = 0; t < 9; ++t) part[t] = 0.f;
#pragma unroll
        for (int i = 0; i < 6; ++i) {
            int c = r + 128 * i;                 // coalesced across the 128-group
            float fval = fvrow[c];
            const float* w = conv_w + (size_t)(1 + c) * 9;
#pragma unroll
            for (int t = 0; t < 9; ++t) part[t] += fval * w[t];
        }
#pragma unroll
        for (int t = 0; t < 9; ++t) {
#pragma unroll
            for (int off = 32; off > 0; off >>= 1)
                part[t] += __shfl_down(part[t], off, 64);
        }
        if ((tid & 63) == 0) {
            int wv = tid >> 6;
#pragma unroll
            for (int t = 0; t < 9; ++t) red[wv][t] = part[t];
        }
    }

    // gWTf row xx = b: gWTf[b*224+o] = sum_w coef(b,w) * W[o][w]
    if (tid < 224) {
        int o = tid;
        float acc = 0.f;
#pragma unroll
        for (int d = -1; d <= 2; ++d) {
            int w = 2 * b + d;
            if (w < 0 || w > 223) continue;
            float hx = clampf(((float)w + 0.5f) * 0.5f - 0.5f, 0.f, 111.f);
            int xx0 = (int)hx; float fx = hx - (float)xx0; int xx1 = min(xx0 + 1, 111);
            float c = (xx0 == b ? 1.f - fx : 0.f) + (xx1 == b ? fx : 0.f);
            acc += c * W_w[o * 224 + w];
        }
        gWTf[b * 224 + o] = acc;
    }
    __syncthreads();
    if (tid < 63) {
        int e7 = tid / 9, t = tid - e7 * 9;
        int e = b * 7 + e7;
        int s = e / 196, uv = e % 196;
        gB[s * 1764 + t * 196 + uv] = red[2 * e7][t] + red[2 * e7 + 1][t];
    }

    cg::this_grid().sync();

    // ======================= Phase B: refine (unchanged) ===================
    // dependence cone of output rows 2b, 2b+1
    int y4lo = max(b - 1, 0), y4hi = min(b + 1, 111);
    int r3lo, r3hi; srcRange(y4lo, y4hi, 56, r3lo, r3hi);
    int r2lo, r2hi; srcRange(r3lo, r3hi, 28, r2lo, r2hi);
    int r1lo, r1hi; srcRange(r2lo, r2hi, 14, r1lo, r1hi);

    // B-plane row windows per stage
    int bl0 = max(r1lo - 1, 0), bh0 = min(r1hi + 1, 13);   // stage 1: integer coords
    int bl1, bh1; bRange(r2lo, r2hi, 28, bl1, bh1);
    int bl2, bh2; bRange(r3lo, r3hi, 56, bl2, bh2);
    int bl3, bh3; bRange(y4lo, y4hi, 112, bl3, bh3);

    // cone-only load of sB (contiguous row windows per (stage, tap) plane)
    {
        int bl[4] = {bl0, bl1, bl2, bl3}, bh[4] = {bh0, bh1, bh2, bh3};
#pragma unroll
        for (int s4 = 0; s4 < 4; ++s4) {
            int nrw = (bh[s4] - bl[s4] + 1) * 14;
            int n = 9 * nrw;
            int base = s4 * 1764 + bl[s4] * 14;
            for (int e = tid; e < n; e += 1024) {
                int t = e / nrw, rem = e % nrw;
                int off = base + t * 196 + rem;
                sB[off] = gB[off];
            }
        }
    }

    float cw[9];
#pragma unroll
    for (int t = 0; t < 9; ++t) cw[t] = conv_w[t];
    float bias = conv_b[0];
    float scale = bng[0] * rsqrtf(bnv[0] + BN_EPS);
    float shift = bnb[0] - bnm[0] * scale;
    __syncthreads();

    // Stage 1 (14x14, h = x, B sampled at integer coords -> direct lookup)
    {
        int n = (r1hi - r1lo + 1) * 14;
        if (tid < n) {
            int i = r1lo + tid / 14, j = tid % 14;
            float acc = bias;
#pragma unroll
            for (int a = 0; a < 3; ++a) {
                int p = i + a - 1;
                if (p < 0 || p >= 14) continue;
#pragma unroll
                for (int bq = 0; bq < 3; ++bq) {
                    int q = j + bq - 1;
                    if (q < 0 || q >= 14) continue;
                    int t = a * 3 + bq;
                    acc += cw[t] * x[p * 14 + q] + sB[t * 196 + p * 14 + q];
                }
            }
            y1s[i * 14 + j] = fmaxf(acc, 0.f) * scale + shift;
        }
    }
    __syncthreads();

    // Stage 2 (28x28)
    {
        int n = (r2hi - r2lo + 1) * 28;
        if (tid < n) {
            int i = r2lo + tid / 28, j = tid % 28;
            float acc = stage_pixel(i, j, 28, y1s, 14, sB + 1764, cw, bias);
            y2s[i * 28 + j] = fmaxf(acc, 0.f) * scale + shift;
        }
    }
    __syncthreads();

    // Stage 3 (56x56)
    {
        int n = (r3hi - r3lo + 1) * 56;
        if (tid < n) {
            int i = r3lo + tid / 56, j = tid % 56;
            float acc = stage_pixel(i, j, 56, y2s, 28, sB + 2 * 1764, cw, bias);
            y3s[i * 56 + j] = fmaxf(acc, 0.f) * scale + shift;
        }
    }
    __syncthreads();

    // Stage 4: rows y4lo..y4hi, slot rr = i-(b-1)
    {
        int n = (y4hi - y4lo + 1) * 112;
        if (tid < n) {
            int i = y4lo + tid / 112, j = tid % 112;
            float acc = stage_pixel(i, j, 112, y3s, 56, sB + 3 * 1764, cw, bias);
            y4loc[(i - (b - 1)) * 112 + j] = fmaxf(acc, 0.f) * scale + shift;
        }
    }
    __syncthreads();

    // D-row dots: D[i][o] = sum_k y4loc[i][k] * gWTf[k][o], K split in 4.
    // One gWTf read feeds 3 FMAs. Garbage slots (unwritten y4loc at the grid
    // edge) produce garbage partials that the final phase never reads.
    if (tid < 896) {
        int kq = tid / 224, o = tid % 224;
        int k0 = kq * 28;
        float a0 = 0.f, a1 = 0.f, a2 = 0.f;
        for (int k = k0; k < k0 + 28; ++k) {
            float wf = gWTf[k * 224 + o];      // coalesced across o
            a0 += y4loc[k] * wf;
            a1 += y4loc[112 + k] * wf;
            a2 += y4loc[224 + k] * wf;
        }
        partial[(0 * 4 + kq) * 224 + o] = a0;
        partial[(1 * 4 + kq) * 224 + o] = a1;
        partial[(2 * 4 + kq) * 224 + o] = a2;
    }
    __syncthreads();

    // up2-y lerp of D rows + bias + sigmoid
    if (tid < 448) {
        int rr = tid / 224, o = tid % 224;
        int r = 2 * b + rr;
        float hy = clampf(((float)r + 0.5f) * 0.5f - 0.5f, 0.f, 111.f);
        int yy0 = (int)hy; float fy = hy - (float)yy0; int yy1 = min(yy0 + 1, 111);
        int s0 = yy0 - (b - 1), s1 = yy1 - (b - 1);   // always in {1,2} at edges
        float D0 = partial[(s0 * 4 + 0) * 224 + o] + partial[(s0 * 4 + 1) * 224 + o]
                 + partial[(s0 * 4 + 2) * 224 + o] + partial[(s0 * 4 + 3) * 224 + o];
        float D1 = partial[(s1 * 4 + 0) * 224 + o] + partial[(s1 * 4 + 1) * 224 + o]
                 + partial[(s1 * 4 + 2) * 224 + o] + partial[(s1 * 4 + 3) * 224 + o];
        float v = (1.f - fy) * D0 + fy * D1 + W_b[o];
        out[(size_t)r * 224 + o] = 1.f / (1.f + expf(-v));
    }
}

extern "C" void kernel_launch(void* const* d_in, const int* in_sizes, int n_in,
                              void* d_out, int out_size, void* d_ws, size_t ws_size,
                              hipStream_t stream) {
    (void)in_sizes; (void)n_in; (void)out_size; (void)ws_size;
    const float* x      = (const float*)d_in[0];
    const float* fv     = (const float*)d_in[1];
    const float* conv_w = (const float*)d_in[2];
    const float* conv_b = (const float*)d_in[3];
    const float* bng    = (const float*)d_in[4];
    const float* bnb    = (const float*)d_in[5];
    const float* bnm    = (const float*)d_in[6];
    const float* bnv    = (const float*)d_in[7];
    const float* W_w    = (const float*)d_in[8];
    const float* W_b    = (const float*)d_in[9];
    float* out = (float*)d_out;

    float* ws   = (float*)d_ws;
    float* gB   = ws;             // 7056 floats
    float* gWTf = ws + 7056;      // 25088 floats (112 x 224)

    void* args[13] = {
        (void*)&x, (void*)&fv, (void*)&conv_w, (void*)&conv_b,
        (void*)&bng, (void*)&bnb, (void*)&bnm, (void*)&bnv,
        (void*)&W_w, (void*)&W_b, (void*)&gB, (void*)&gWTf, (void*)&out
    };
    hipLaunchCooperativeKernel((void*)refine_fused, dim3(112), dim3(1024),
                               args, 0, stream);
}